// Round 5
// baseline (673.022 us; speedup 1.0000x reference)
//
#include <hip/hip_runtime.h>
#include <hip/hip_bf16.h>
#include <math.h>

#define N_NODES 100000
#define N_EDGES 1600000
#define D 64
#define DOUT 10
#define CAP 64
#define APAD 136     // LDS row stride (bf16 elems): 272B = 17*16B
#define NB 782       // ceil(N_NODES / 128) dst-bins
#define BCAP 2368    // per-bin edge capacity: mean 2046, +7 sigma

typedef __attribute__((ext_vector_type(8))) short short8;
typedef __attribute__((ext_vector_type(4))) float f32x4;

__device__ __forceinline__ unsigned short f2bf(float f) {
    __hip_bfloat16 h = __float2bfloat16(f);
    return __builtin_bit_cast(unsigned short, h);
}
__device__ __forceinline__ float blo(unsigned v) { return __builtin_bit_cast(float, v << 16); }
__device__ __forceinline__ float bhi(unsigned v) { return __builtin_bit_cast(float, v & 0xFFFF0000u); }

// ---------------- fill path: bin cursors -> partition -> LDS build ----------------
__global__ void init_kernel(int* __restrict__ binPos) {
    int i = blockIdx.x * blockDim.x + threadIdx.x;
    if (i < NB) binPos[i] = i * BCAP;
}

__global__ void scatter_kernel(const int* __restrict__ src, const int* __restrict__ dst,
                               int* __restrict__ binPos, int* __restrict__ ebuf) {
    int e = blockIdx.x * blockDim.x + threadIdx.x;
    if (e >= N_EDGES) return;
    int d = dst[e];
    int b = d >> 7;
    int p = atomicAdd(&binPos[b], 1);
    if (p < (b + 1) * BCAP) ebuf[p] = (src[e] << 7) | (d & 127);  // src<2^17, 24 bits total
}

__global__ __launch_bounds__(256) void build_kernel(const int* __restrict__ ebuf,
                                                    const int* __restrict__ binPos,
                                                    int* __restrict__ cnt,
                                                    int* __restrict__ bucket) {
    __shared__ int lb[128 * CAP];   // 32 KB
    __shared__ int lcnt[128];
    int b = blockIdx.x;
    int tid = threadIdx.x;
    for (int i = tid; i < 128 * CAP; i += 256) lb[i] = N_NODES;  // sentinel -> zero row
    if (tid < 128) lcnt[tid] = 0;
    __syncthreads();
    int e0 = b * BCAP;
    int e1 = binPos[b];
    int ecap = e0 + BCAP;
    if (e1 > ecap) e1 = ecap;
    for (int e = e0 + tid; e < e1; e += 256) {
        int v = ebuf[e];
        int dloc = v & 127;
        int s = v >> 7;
        int p = atomicAdd(&lcnt[dloc], 1);
        if (p < CAP) lb[dloc * CAP + p] = s;
    }
    __syncthreads();
    int nodeBase = b * 128;
    int lastNode = N_NODES - nodeBase;   // valid dloc < lastNode
    for (int i = tid; i < 128 * CAP / 4; i += 256) {
        int dloc = (i * 4) >> 6;
        if (dloc < lastNode)
            *(int4*)&bucket[(size_t)nodeBase * CAP + i * 4] = *(const int4*)&lb[i * 4];
    }
    if (tid < 128 && tid < lastNode) cnt[nodeBase + tid] = lcnt[tid];
}

// ---------------- x (f32) -> xb (bf16), plus zero sentinel row N ----------------
__global__ void cvt_kernel(const float* __restrict__ x, unsigned short* __restrict__ xb) {
    int i = blockIdx.x * blockDim.x + threadIdx.x;
    const int total = (N_NODES + 1) * D / 4;
    if (i >= total) return;
    ushort4 o;
    if (i * 4 < N_NODES * D) {
        float4 v = *(const float4*)&x[i * 4];
        o.x = f2bf(v.x); o.y = f2bf(v.y); o.z = f2bf(v.z); o.w = f2bf(v.w);
    } else {
        o.x = 0; o.y = 0; o.z = 0; o.w = 0;
    }
    *(ushort4*)&xb[i * 4] = o;
}

// --------- pre-transpose weights to Wt[col j][k] bf16 (k<64: W_out, k>=64: W_root) ---------
__global__ void prep_w_kernel(const float* __restrict__ W_out0, const float* __restrict__ W_root0,
                              const float* __restrict__ W_out1, const float* __restrict__ W_root1,
                              const float* __restrict__ W_out2, const float* __restrict__ W_root2,
                              unsigned short* __restrict__ Wt0, unsigned short* __restrict__ Wt1,
                              unsigned short* __restrict__ Wt2) {
    int idx = blockIdx.x * blockDim.x + threadIdx.x;
    if (idx < 8192) {
        int j = idx >> 7, k = idx & 127;
        float v = k < 64 ? W_out0[k * D + j] : W_root0[(k - 64) * D + j];
        Wt0[idx] = f2bf(v);
    } else if (idx < 16384) {
        int t = idx - 8192;
        int j = t >> 7, k = t & 127;
        float v = k < 64 ? W_out1[k * D + j] : W_root1[(k - 64) * D + j];
        Wt1[t] = f2bf(v);
    } else if (idx < 16384 + 2048) {
        int t = idx - 16384;
        int j = t >> 7, k = t & 127;
        float v = 0.f;
        if (j < DOUT) v = k < 64 ? W_out2[k * DOUT + j] : W_root2[(k - 64) * DOUT + j];
        Wt2[t] = f2bf(v);
    }
}

#define RED(mask) \
    a0 += __shfl_xor(a0, mask, 64); a1 += __shfl_xor(a1, mask, 64); \
    a2 += __shfl_xor(a2, mask, 64); a3 += __shfl_xor(a3, mask, 64); \
    a4 += __shfl_xor(a4, mask, 64); a5 += __shfl_xor(a5, mask, 64); \
    a6 += __shfl_xor(a6, mask, 64); a7 += __shfl_xor(a7, mask, 64);

// Gather one node's mean-aggregate: lane (g=lane>>3, j=lane&7) loads neighbor (it*8+g)'s
// 16B chunk j (8 bf16) -> 8 neighbor rows per memory instruction. Result: lanes g==0
// hold features j*8..j*8+7 (all lanes hold them after full butterfly).
#define GATHER_NODE(A_lds)                                                            \
    {                                                                                 \
        int c = 0, bl = N_NODES;                                                      \
        if (node < N_NODES) {                                                         \
            c = cnt[node];                                                            \
            bl = bucket[(size_t)node * CAP + lane];                                   \
        }                                                                             \
        int cc = c < CAP ? c : CAP;                                                   \
        float a0 = 0.f, a1 = 0.f, a2 = 0.f, a3 = 0.f,                                 \
              a4 = 0.f, a5 = 0.f, a6 = 0.f, a7 = 0.f;                                 \
        int niter = (cc + 7) >> 3;                                                    \
        for (int it = 0; it < niter; ++it) {                                          \
            int s = __builtin_amdgcn_ds_bpermute(((it << 3) + g) << 2, bl);           \
            uint4 dv = *(const uint4*)&in[(size_t)s * D + j * 8];                     \
            a0 += blo(dv.x); a1 += bhi(dv.x);                                         \
            a2 += blo(dv.y); a3 += bhi(dv.y);                                         \
            a4 += blo(dv.z); a5 += bhi(dv.z);                                         \
            a6 += blo(dv.w); a7 += bhi(dv.w);                                         \
        }                                                                             \
        float dinv = 1.0f / (float)(c > 0 ? c : 1);                                   \
        a0 *= dinv; a1 *= dinv; a2 *= dinv; a3 *= dinv;                               \
        a4 *= dinv; a5 *= dinv; a6 *= dinv; a7 *= dinv;                               \
        RED(8) RED(16) RED(32)                                                        \
        if (g == 0) {                                                                 \
            uint4 pk;                                                                 \
            pk.x = (unsigned)f2bf(a0) | ((unsigned)f2bf(a1) << 16);                   \
            pk.y = (unsigned)f2bf(a2) | ((unsigned)f2bf(a3) << 16);                   \
            pk.z = (unsigned)f2bf(a4) | ((unsigned)f2bf(a5) << 16);                   \
            pk.w = (unsigned)f2bf(a6) | ((unsigned)f2bf(a7) << 16);                   \
            *(uint4*)&A_lds[nl * APAD + j * 8] = pk;                                  \
        }                                                                             \
    }

// ---------------- hidden layer: 64-node tile; wide gather -> LDS A[64][128] -> MFMA ----------------
__global__ __launch_bounds__(256) void layer_mfma_kernel(
    const unsigned short* __restrict__ in, unsigned short* __restrict__ out,
    const int* __restrict__ cnt, const int* __restrict__ bucket,
    const unsigned short* __restrict__ Wt_g, const float* __restrict__ bias_v) {
    __shared__ __align__(16) unsigned short A[64 * APAD];
    __shared__ __align__(16) unsigned short Wt[64 * APAD];
    int tid = threadIdx.x;
    for (int idx = tid; idx < 64 * 128; idx += 256)
        Wt[(idx >> 7) * APAD + (idx & 127)] = Wt_g[idx];

    int base = blockIdx.x * 64;
    // x-half of A: contiguous block copy (no gather needed for the root term)
    for (int idx = tid; idx < 512; idx += 256) {
        int r = idx >> 3, ch = idx & 7;
        int nd = base + r;
        if (nd > N_NODES) nd = N_NODES;
        uint4 v = *(const uint4*)&in[(size_t)nd * D + ch * 8];
        *(uint4*)&A[r * APAD + D + ch * 8] = v;
    }

    int lane = tid & 63, w = tid >> 6;
    int g = lane >> 3, j = lane & 7;
    for (int i = 0; i < 16; ++i) {
        int nl = w * 16 + i;
        int node = base + nl;
        GATHER_NODE(A)
    }
    __syncthreads();

    // MFMA: wave w computes rows w*16..+15 x 64 cols, K=128
    int r16 = lane & 15, g4 = lane >> 4;
    f32x4 acc[4] = {{0.f,0.f,0.f,0.f},{0.f,0.f,0.f,0.f},{0.f,0.f,0.f,0.f},{0.f,0.f,0.f,0.f}};
    int arow = w * 16 + r16;
#pragma unroll
    for (int ks = 0; ks < 4; ++ks) {
        int koff = ks * 32 + g4 * 8;
        short8 a = *(const short8*)&A[arow * APAD + koff];
#pragma unroll
        for (int n = 0; n < 4; ++n) {
            short8 bfr = *(const short8*)&Wt[(n * 16 + r16) * APAD + koff];
            acc[n] = __builtin_amdgcn_mfma_f32_16x16x32_bf16(a, bfr, acc[n], 0, 0, 0);
        }
    }
#pragma unroll
    for (int n = 0; n < 4; ++n) {
        int col = n * 16 + r16;
        float bias = bias_v[col];
#pragma unroll
        for (int r = 0; r < 4; ++r) {
            int node = base + w * 16 + g4 * 4 + r;
            if (node <= N_NODES) {   // row N = sentinel zero row
                float v = node < N_NODES ? fmaxf(acc[n][r] + bias, 0.f) : 0.f;
                out[(size_t)node * D + col] = f2bf(v);
            }
        }
    }
}

// ---------------- output layer: wide gather; N=16 cols (10 real); fused log_softmax ----------------
__global__ __launch_bounds__(256) void layer_out_mfma_kernel(
    const unsigned short* __restrict__ in, float* __restrict__ out,
    const int* __restrict__ cnt, const int* __restrict__ bucket,
    const unsigned short* __restrict__ Wt_g, const float* __restrict__ bias_v) {
    __shared__ __align__(16) unsigned short A[64 * APAD];
    __shared__ __align__(16) unsigned short Wt[16 * APAD];
    int tid = threadIdx.x;
    for (int idx = tid; idx < 16 * 128; idx += 256)
        Wt[(idx >> 7) * APAD + (idx & 127)] = Wt_g[idx];

    int base = blockIdx.x * 64;
    for (int idx = tid; idx < 512; idx += 256) {
        int r = idx >> 3, ch = idx & 7;
        int nd = base + r;
        if (nd > N_NODES) nd = N_NODES;
        uint4 v = *(const uint4*)&in[(size_t)nd * D + ch * 8];
        *(uint4*)&A[r * APAD + D + ch * 8] = v;
    }

    int lane = tid & 63, w = tid >> 6;
    int g = lane >> 3, j = lane & 7;
    for (int i = 0; i < 16; ++i) {
        int nl = w * 16 + i;
        int node = base + nl;
        GATHER_NODE(A)
    }
    __syncthreads();

    int r16 = lane & 15, g4 = lane >> 4;
    f32x4 acc = {0.f, 0.f, 0.f, 0.f};
    int arow = w * 16 + r16;
#pragma unroll
    for (int ks = 0; ks < 4; ++ks) {
        int koff = ks * 32 + g4 * 8;
        short8 a = *(const short8*)&A[arow * APAD + koff];
        short8 bfr = *(const short8*)&Wt[r16 * APAD + koff];
        acc = __builtin_amdgcn_mfma_f32_16x16x32_bf16(a, bfr, acc, 0, 0, 0);
    }
    float bias = r16 < DOUT ? bias_v[r16] : -1e30f;   // pad cols -> exp()=0
#pragma unroll
    for (int r = 0; r < 4; ++r) {
        float v = acc[r] + bias;
        float m = v;
        m = fmaxf(m, __shfl_xor(m, 1, 16));
        m = fmaxf(m, __shfl_xor(m, 2, 16));
        m = fmaxf(m, __shfl_xor(m, 4, 16));
        m = fmaxf(m, __shfl_xor(m, 8, 16));
        float e = expf(v - m);
        float s = e;
        s += __shfl_xor(s, 1, 16);
        s += __shfl_xor(s, 2, 16);
        s += __shfl_xor(s, 4, 16);
        s += __shfl_xor(s, 8, 16);
        int node = base + w * 16 + g4 * 4 + r;
        if (node < N_NODES && r16 < DOUT)
            out[(size_t)node * DOUT + r16] = v - m - logf(s);
    }
}

extern "C" void kernel_launch(void* const* d_in, const int* in_sizes, int n_in,
                              void* d_out, int out_size, void* d_ws, size_t ws_size,
                              hipStream_t stream) {
    const float* x       = (const float*)d_in[0];
    const int*   ei      = (const int*)d_in[1];
    const int*   src     = ei;            // edge_index[0]
    const int*   dst     = ei + N_EDGES;  // edge_index[1]
    const float* W_out0  = (const float*)d_in[2];
    const float* b0      = (const float*)d_in[3];
    const float* W_root0 = (const float*)d_in[4];
    const float* W_out1  = (const float*)d_in[5];
    const float* b1      = (const float*)d_in[6];
    const float* W_root1 = (const float*)d_in[7];
    const float* W_out2  = (const float*)d_in[8];
    const float* b2      = (const float*)d_in[9];
    const float* W_root2 = (const float*)d_in[10];
    float* outp = (float*)d_out;

    // ws: xb|h0|h1 ((N+1)*64 bf16 each, row N = zeros) | Wt0|Wt1 (8192) | Wt2 (2048)
    //     | cnt (N i32) | bucket (N*64 i32) | binPos (1024 i32) | ebuf (NB*BCAP i32)  ~72 MB
    const size_t ROWS = (size_t)(N_NODES + 1) * D;
    unsigned short* xb  = (unsigned short*)d_ws;
    unsigned short* h0  = xb + ROWS;
    unsigned short* h1  = h0 + ROWS;
    unsigned short* Wt0 = h1 + ROWS;
    unsigned short* Wt1 = Wt0 + 8192;
    unsigned short* Wt2 = Wt1 + 8192;
    int* cnt    = (int*)(Wt2 + 2048);
    int* bucket = cnt + N_NODES;
    int* binPos = bucket + (size_t)N_NODES * CAP;
    int* ebuf   = binPos + 1024;

    init_kernel<<<(NB + 255) / 256, 256, 0, stream>>>(binPos);
    scatter_kernel<<<(N_EDGES + 255) / 256, 256, 0, stream>>>(src, dst, binPos, ebuf);
    build_kernel<<<NB, 256, 0, stream>>>(ebuf, binPos, cnt, bucket);
    cvt_kernel<<<((N_NODES + 1) * D / 4 + 255) / 256, 256, 0, stream>>>(x, xb);
    prep_w_kernel<<<(16384 + 2048 + 255) / 256, 256, 0, stream>>>(
        W_out0, W_root0, W_out1, W_root1, W_out2, W_root2, Wt0, Wt1, Wt2);

    const int tiles = (N_NODES + 63) / 64;  // 1563 (covers sentinel row N in layer outputs)
    layer_mfma_kernel<<<tiles, 256, 0, stream>>>(xb, h0, cnt, bucket, Wt0, b0);
    layer_mfma_kernel<<<tiles, 256, 0, stream>>>(h0, h1, cnt, bucket, Wt1, b1);
    layer_out_mfma_kernel<<<tiles, 256, 0, stream>>>(h1, outp, cnt, bucket, Wt2, b2);
}

// Round 6
// 371.151 us; speedup vs baseline: 1.8133x; 1.8133x over previous
//
#include <hip/hip_runtime.h>
#include <hip/hip_bf16.h>
#include <math.h>

#define N_NODES 100000
#define N_EDGES 1600000
#define D 64
#define DOUT 10
#define CAP 64
#define APAD 136   // LDS row stride (bf16): 272B, 16B-aligned

typedef __attribute__((ext_vector_type(8))) short short8;
typedef __attribute__((ext_vector_type(4))) float f32x4;

__device__ __forceinline__ unsigned short f2bf(float f) {
    __hip_bfloat16 h = __float2bfloat16(f);
    return __builtin_bit_cast(unsigned short, h);
}
__device__ __forceinline__ float blo(unsigned v) { return __builtin_bit_cast(float, v << 16); }
__device__ __forceinline__ float bhi(unsigned v) { return __builtin_bit_cast(float, v & 0xFFFF0000u); }

// ---------------- bucket build: one int atomic per edge (direct; ~write-amp floor) ----------------
__global__ void fill_kernel(const int* __restrict__ src, const int* __restrict__ dst,
                            int* __restrict__ cnt, int* __restrict__ bucket) {
    int e = blockIdx.x * blockDim.x + threadIdx.x;
    if (e >= N_EDGES) return;
    int d = dst[e];
    int p = atomicAdd(&cnt[d], 1);
    if (p < CAP) __builtin_nontemporal_store(src[e], &bucket[d * CAP + p]);
}

// ---------------- x (f32) -> xb (bf16), plus zero sentinel row N ----------------
__global__ void cvt_kernel(const float* __restrict__ x, unsigned short* __restrict__ xb) {
    int i = blockIdx.x * blockDim.x + threadIdx.x;
    const int total = (N_NODES + 1) * D / 4;
    if (i >= total) return;
    ushort4 o;
    if (i * 4 < N_NODES * D) {
        float4 v = *(const float4*)&x[i * 4];
        o.x = f2bf(v.x); o.y = f2bf(v.y); o.z = f2bf(v.z); o.w = f2bf(v.w);
    } else {
        o.x = 0; o.y = 0; o.z = 0; o.w = 0;
    }
    *(ushort4*)&xb[i * 4] = o;
}

// --------- pre-transpose weights to Wt[col j][k] bf16 (k<64: W_out, k>=64: W_root) ---------
__global__ void prep_w_kernel(const float* __restrict__ W_out0, const float* __restrict__ W_root0,
                              const float* __restrict__ W_out1, const float* __restrict__ W_root1,
                              const float* __restrict__ W_out2, const float* __restrict__ W_root2,
                              unsigned short* __restrict__ Wt0, unsigned short* __restrict__ Wt1,
                              unsigned short* __restrict__ Wt2) {
    int idx = blockIdx.x * blockDim.x + threadIdx.x;
    if (idx < 8192) {
        int j = idx >> 7, k = idx & 127;
        float v = k < 64 ? W_out0[k * D + j] : W_root0[(k - 64) * D + j];
        Wt0[idx] = f2bf(v);
    } else if (idx < 16384) {
        int t = idx - 8192;
        int j = t >> 7, k = t & 127;
        float v = k < 64 ? W_out1[k * D + j] : W_root1[(k - 64) * D + j];
        Wt1[t] = f2bf(v);
    } else if (idx < 16384 + 2048) {
        int t = idx - 16384;
        int j = t >> 7, k = t & 127;
        float v = 0.f;
        if (j < DOUT) v = k < 64 ? W_out2[k * DOUT + j] : W_root2[(k - 64) * DOUT + j];
        Wt2[t] = f2bf(v);
    }
}

#define ACC8(va, r) { va[0] += blo(r.x); va[1] += bhi(r.x); va[2] += blo(r.y); va[3] += bhi(r.y); \
                      va[4] += blo(r.z); va[5] += bhi(r.z); va[6] += blo(r.w); va[7] += bhi(r.w); }

// ---------------- gather: mean-aggregate neighbors -> agg (bf16), 2 nodes per wave-iter --------
// lane (g=lane>>3, j=lane&7): one instruction reads 8 neighbors' 16B chunks (1KB/instr).
// No LDS, ~40 VGPR -> full occupancy; idx prefetch + 2-node interleave for MLP.
__global__ __launch_bounds__(256) void gather_kernel(
    const unsigned short* __restrict__ in, unsigned short* __restrict__ agg,
    const int* __restrict__ cnt, const int* __restrict__ bucket) {
    int tid = threadIdx.x;
    int lane = tid & 63;
    int g = lane >> 3, j = lane & 7;
    int wv = (blockIdx.x * blockDim.x + tid) >> 6;
    int nw = (gridDim.x * blockDim.x) >> 6;
    const int NPAIR = (N_NODES + 2) / 2;   // covers nodes 0..100000 (incl. sentinel row N)

    for (int pr = wv; pr < NPAIR; pr += nw) {
        int n0 = pr * 2;
        int n1 = n0 + 1;
        int c0 = (n0 < N_NODES) ? cnt[n0] : 0;
        int c1 = (n1 < N_NODES) ? cnt[n1] : 0;
        int cc0 = c0 < CAP ? c0 : CAP;
        int cc1 = c1 < CAP ? c1 : CAP;
        int ni0 = (cc0 + 7) >> 3, ni1 = (cc1 + 7) >> 3;
        int nmax = ni0 > ni1 ? ni0 : ni1;
        const int* brow0 = &bucket[(size_t)(n0 < N_NODES ? n0 : 0) * CAP];
        const int* brow1 = &bucket[(size_t)(n1 < N_NODES ? n1 : 0) * CAP];

        float va[8] = {0.f,0.f,0.f,0.f,0.f,0.f,0.f,0.f};
        float vb[8] = {0.f,0.f,0.f,0.f,0.f,0.f,0.f,0.f};
        int i0 = brow0[g];          // idx prefetch it=0 (8 consecutive ints -> one 32B fetch)
        int i1 = brow1[g];
        for (int it = 0; it < nmax; ++it) {
            int slot = it * 8 + g;
            int p0 = (it + 1 < nmax) ? brow0[slot + 8] : 0;   // prefetch next idx
            int p1 = (it + 1 < nmax) ? brow1[slot + 8] : 0;
            int s0 = (slot < cc0) ? i0 : N_NODES;             // mask pad slots -> zero row
            int s1 = (slot < cc1) ? i1 : N_NODES;
            uint4 r0 = *(const uint4*)&in[(size_t)s0 * D + j * 8];
            uint4 r1 = *(const uint4*)&in[(size_t)s1 * D + j * 8];
            ACC8(va, r0)
            ACC8(vb, r1)
            i0 = p0; i1 = p1;
        }
        // reduce across neighbor-groups g (lanes with equal j)
#pragma unroll
        for (int m = 8; m <= 32; m <<= 1) {
#pragma unroll
            for (int k = 0; k < 8; ++k) {
                va[k] += __shfl_xor(va[k], m, 64);
                vb[k] += __shfl_xor(vb[k], m, 64);
            }
        }
        float d0 = 1.0f / (float)(c0 > 0 ? c0 : 1);
        float d1 = 1.0f / (float)(c1 > 0 ? c1 : 1);
        if (g == 0) {
            uint4 pk;
            pk.x = (unsigned)f2bf(va[0] * d0) | ((unsigned)f2bf(va[1] * d0) << 16);
            pk.y = (unsigned)f2bf(va[2] * d0) | ((unsigned)f2bf(va[3] * d0) << 16);
            pk.z = (unsigned)f2bf(va[4] * d0) | ((unsigned)f2bf(va[5] * d0) << 16);
            pk.w = (unsigned)f2bf(va[6] * d0) | ((unsigned)f2bf(va[7] * d0) << 16);
            *(uint4*)&agg[(size_t)n0 * D + j * 8] = pk;
        } else if (g == 1 && n1 <= N_NODES) {
            uint4 pk;
            pk.x = (unsigned)f2bf(vb[0] * d1) | ((unsigned)f2bf(vb[1] * d1) << 16);
            pk.y = (unsigned)f2bf(vb[2] * d1) | ((unsigned)f2bf(vb[3] * d1) << 16);
            pk.z = (unsigned)f2bf(vb[4] * d1) | ((unsigned)f2bf(vb[5] * d1) << 16);
            pk.w = (unsigned)f2bf(vb[6] * d1) | ((unsigned)f2bf(vb[7] * d1) << 16);
            *(uint4*)&agg[(size_t)n1 * D + j * 8] = pk;
        }
    }
}

// ---------------- dense hidden GEMM: C = relu([agg|x] @ Wcat + b), 64-node tile ----------------
__global__ __launch_bounds__(256) void gemm_hidden_kernel(
    const unsigned short* __restrict__ agg, const unsigned short* __restrict__ xin,
    unsigned short* __restrict__ out, const unsigned short* __restrict__ Wt_g,
    const float* __restrict__ bias_v) {
    __shared__ __align__(16) unsigned short Wt[64 * APAD];
    int tid = threadIdx.x;
#pragma unroll
    for (int i = 0; i < 4; ++i) {
        int e = (tid + i * 256) * 8;
        uint4 v = *(const uint4*)&Wt_g[e];
        *(uint4*)&Wt[(e >> 7) * APAD + (e & 127)] = v;
    }
    __syncthreads();

    int lane = tid & 63, w = tid >> 6;
    int r16 = lane & 15, g4 = lane >> 4;
    int base = blockIdx.x * 64;
    int arow = base + w * 16 + r16;
    int nd = arow < N_NODES ? arow : N_NODES;   // clamp to sentinel zero row

    f32x4 acc[4] = {{0.f,0.f,0.f,0.f},{0.f,0.f,0.f,0.f},{0.f,0.f,0.f,0.f},{0.f,0.f,0.f,0.f}};
#pragma unroll
    for (int ks = 0; ks < 4; ++ks) {
        int koff = ks * 32 + g4 * 8;
        short8 a;
        if (ks < 2) a = *(const short8*)&agg[(size_t)nd * D + koff];
        else        a = *(const short8*)&xin[(size_t)nd * D + (koff - 64)];
#pragma unroll
        for (int n = 0; n < 4; ++n) {
            short8 b = *(const short8*)&Wt[(n * 16 + r16) * APAD + koff];
            acc[n] = __builtin_amdgcn_mfma_f32_16x16x32_bf16(a, b, acc[n], 0, 0, 0);
        }
    }
#pragma unroll
    for (int n = 0; n < 4; ++n) {
        int col = n * 16 + r16;
        float bias = bias_v[col];
#pragma unroll
        for (int r = 0; r < 4; ++r) {
            int node = base + w * 16 + g4 * 4 + r;
            if (node <= N_NODES) {   // row N: keep sentinel zero (bias must not leak in)
                float v = node < N_NODES ? fmaxf(acc[n][r] + bias, 0.f) : 0.f;
                out[(size_t)node * D + col] = f2bf(v);
            }
        }
    }
}

// ---------------- output GEMM (64->10) + fused log_softmax ----------------
__global__ __launch_bounds__(256) void gemm_out_kernel(
    const unsigned short* __restrict__ agg, const unsigned short* __restrict__ xin,
    float* __restrict__ out, const unsigned short* __restrict__ Wt_g,
    const float* __restrict__ bias_v) {
    __shared__ __align__(16) unsigned short Wt[16 * APAD];
    int tid = threadIdx.x;
    {
        int e = tid * 8;
        uint4 v = *(const uint4*)&Wt_g[e];
        *(uint4*)&Wt[(e >> 7) * APAD + (e & 127)] = v;
    }
    __syncthreads();

    int lane = tid & 63, w = tid >> 6;
    int r16 = lane & 15, g4 = lane >> 4;
    int base = blockIdx.x * 64;
    int arow = base + w * 16 + r16;
    int nd = arow < N_NODES ? arow : N_NODES;

    f32x4 acc = {0.f, 0.f, 0.f, 0.f};
#pragma unroll
    for (int ks = 0; ks < 4; ++ks) {
        int koff = ks * 32 + g4 * 8;
        short8 a;
        if (ks < 2) a = *(const short8*)&agg[(size_t)nd * D + koff];
        else        a = *(const short8*)&xin[(size_t)nd * D + (koff - 64)];
        short8 b = *(const short8*)&Wt[r16 * APAD + koff];
        acc = __builtin_amdgcn_mfma_f32_16x16x32_bf16(a, b, acc, 0, 0, 0);
    }
    float bias = r16 < DOUT ? bias_v[r16] : -1e30f;   // pad cols -> exp()=0
#pragma unroll
    for (int r = 0; r < 4; ++r) {
        float v = acc[r] + bias;
        float m = v;
        m = fmaxf(m, __shfl_xor(m, 1, 16));
        m = fmaxf(m, __shfl_xor(m, 2, 16));
        m = fmaxf(m, __shfl_xor(m, 4, 16));
        m = fmaxf(m, __shfl_xor(m, 8, 16));
        float e = expf(v - m);
        float s = e;
        s += __shfl_xor(s, 1, 16);
        s += __shfl_xor(s, 2, 16);
        s += __shfl_xor(s, 4, 16);
        s += __shfl_xor(s, 8, 16);
        int node = base + w * 16 + g4 * 4 + r;
        if (node < N_NODES && r16 < DOUT)
            out[(size_t)node * DOUT + r16] = v - m - logf(s);
    }
}

extern "C" void kernel_launch(void* const* d_in, const int* in_sizes, int n_in,
                              void* d_out, int out_size, void* d_ws, size_t ws_size,
                              hipStream_t stream) {
    const float* x       = (const float*)d_in[0];
    const int*   ei      = (const int*)d_in[1];
    const int*   src     = ei;            // edge_index[0]
    const int*   dst     = ei + N_EDGES;  // edge_index[1]
    const float* W_out0  = (const float*)d_in[2];
    const float* b0      = (const float*)d_in[3];
    const float* W_root0 = (const float*)d_in[4];
    const float* W_out1  = (const float*)d_in[5];
    const float* b1      = (const float*)d_in[6];
    const float* W_root1 = (const float*)d_in[7];
    const float* W_out2  = (const float*)d_in[8];
    const float* b2      = (const float*)d_in[9];
    const float* W_root2 = (const float*)d_in[10];
    float* outp = (float*)d_out;

    // ws: xb | h0 | h1 ((N+1)*64 bf16 each; agg scratch rotates through the free one)
    //     | Wt0 | Wt1 (8192) | Wt2 (2048) | cnt (N i32) | bucket (N*64 i32)   ~64.4 MB
    const size_t ROWS = (size_t)(N_NODES + 1) * D;
    unsigned short* xb  = (unsigned short*)d_ws;
    unsigned short* h0  = xb + ROWS;
    unsigned short* h1  = h0 + ROWS;
    unsigned short* Wt0 = h1 + ROWS;
    unsigned short* Wt1 = Wt0 + 8192;
    unsigned short* Wt2 = Wt1 + 8192;
    int* cnt    = (int*)(Wt2 + 2048);
    int* bucket = cnt + N_NODES;

    hipMemsetAsync(cnt, 0, N_NODES * sizeof(int), stream);
    fill_kernel<<<(N_EDGES + 255) / 256, 256, 0, stream>>>(src, dst, cnt, bucket);
    cvt_kernel<<<((N_NODES + 1) * D / 4 + 255) / 256, 256, 0, stream>>>(x, xb);
    prep_w_kernel<<<(16384 + 2048 + 255) / 256, 256, 0, stream>>>(
        W_out0, W_root0, W_out1, W_root1, W_out2, W_root2, Wt0, Wt1, Wt2);

    const int GB = 2048;                      // gather: full-occupancy grid-stride
    const int tiles = (N_NODES + 63) / 64;    // 1563 GEMM tiles
    // layer 0: agg -> h1 (free), gemm -> h0
    gather_kernel<<<GB, 256, 0, stream>>>(xb, h1, cnt, bucket);
    gemm_hidden_kernel<<<tiles, 256, 0, stream>>>(h1, xb, h0, Wt0, b0);
    // layer 1: agg -> xb (free), gemm -> h1
    gather_kernel<<<GB, 256, 0, stream>>>(h0, xb, cnt, bucket);
    gemm_hidden_kernel<<<tiles, 256, 0, stream>>>(xb, h0, h1, Wt1, b1);
    // layer 2: agg -> h0 (free), gemm -> out
    gather_kernel<<<GB, 256, 0, stream>>>(h1, h0, cnt, bucket);
    gemm_out_kernel<<<tiles, 256, 0, stream>>>(h0, h1, outp, Wt2, b2);
}

// Round 7
// 349.243 us; speedup vs baseline: 1.9271x; 1.0627x over previous
//
#include <hip/hip_runtime.h>
#include <hip/hip_bf16.h>
#include <math.h>

#define N_NODES 100000
#define N_EDGES 1600000
#define D 64
#define DOUT 10
#define CAP 64
#define APAD 136   // LDS row stride (bf16): 272B, 16B-aligned

typedef __attribute__((ext_vector_type(8))) short short8;
typedef __attribute__((ext_vector_type(4))) float f32x4;

__device__ __forceinline__ unsigned short f2bf(float f) {
    __hip_bfloat16 h = __float2bfloat16(f);
    return __builtin_bit_cast(unsigned short, h);
}
__device__ __forceinline__ float blo(unsigned v) { return __builtin_bit_cast(float, v << 16); }
__device__ __forceinline__ float bhi(unsigned v) { return __builtin_bit_cast(float, v & 0xFFFF0000u); }

// ---------------- XCD-sliced bucket build ----------------
// Group g = blockIdx&7 (dispatch round-robins XCDs) owns dst range [g*12500,(g+1)*12500):
// its bucket slice (3.2 MB) + cnt slice stay in ONE XCD's L2, so scatter lines fill up
// before eviction (write-amp ~1x instead of ~15x). Each group scans the full edge list
// (nontemporal reads, L3-served). Correct regardless of the XCD mapping.
__global__ __launch_bounds__(256) void fill_kernel(const int* __restrict__ src,
                                                   const int* __restrict__ dst,
                                                   int* __restrict__ cnt,
                                                   int* __restrict__ bucket) {
    const int SLICE = (N_NODES + 7) / 8;   // 12500
    int g = blockIdx.x & 7;
    int q = blockIdx.x >> 3;
    int nblk = gridDim.x >> 3;
    int lo = g * SLICE;
    int hi = lo + SLICE; if (hi > N_NODES) hi = N_NODES;
    for (int e = q * 256 + (int)threadIdx.x; e < N_EDGES; e += nblk * 256) {
        int d = __builtin_nontemporal_load(dst + e);
        if (d >= lo && d < hi) {
            int s = __builtin_nontemporal_load(src + e);
            int p = atomicAdd(&cnt[d], 1);
            if (p < CAP) bucket[(size_t)d * CAP + p] = s;
        }
    }
}

// ---------------- x (f32) -> xb (bf16), plus zero sentinel row N ----------------
__global__ void cvt_kernel(const float* __restrict__ x, unsigned short* __restrict__ xb) {
    int i = blockIdx.x * blockDim.x + threadIdx.x;
    const int total = (N_NODES + 1) * D / 4;
    if (i >= total) return;
    ushort4 o;
    if (i * 4 < N_NODES * D) {
        float4 v = *(const float4*)&x[i * 4];
        o.x = f2bf(v.x); o.y = f2bf(v.y); o.z = f2bf(v.z); o.w = f2bf(v.w);
    } else {
        o.x = 0; o.y = 0; o.z = 0; o.w = 0;
    }
    *(ushort4*)&xb[i * 4] = o;
}

// --------- pre-transpose weights to Wt[col j][k] bf16 (k<64: W_out, k>=64: W_root) ---------
__global__ void prep_w_kernel(const float* __restrict__ W_out0, const float* __restrict__ W_root0,
                              const float* __restrict__ W_out1, const float* __restrict__ W_root1,
                              const float* __restrict__ W_out2, const float* __restrict__ W_root2,
                              unsigned short* __restrict__ Wt0, unsigned short* __restrict__ Wt1,
                              unsigned short* __restrict__ Wt2) {
    int idx = blockIdx.x * blockDim.x + threadIdx.x;
    if (idx < 8192) {
        int j = idx >> 7, k = idx & 127;
        float v = k < 64 ? W_out0[k * D + j] : W_root0[(k - 64) * D + j];
        Wt0[idx] = f2bf(v);
    } else if (idx < 16384) {
        int t = idx - 8192;
        int j = t >> 7, k = t & 127;
        float v = k < 64 ? W_out1[k * D + j] : W_root1[(k - 64) * D + j];
        Wt1[t] = f2bf(v);
    } else if (idx < 16384 + 2048) {
        int t = idx - 16384;
        int j = t >> 7, k = t & 127;
        float v = 0.f;
        if (j < DOUT) v = k < 64 ? W_out2[k * DOUT + j] : W_root2[(k - 64) * DOUT + j];
        Wt2[t] = f2bf(v);
    }
}

#define ACC8(va, r) { va[0] += blo(r.x); va[1] += bhi(r.x); va[2] += blo(r.y); va[3] += bhi(r.y); \
                      va[4] += blo(r.z); va[5] += bhi(r.z); va[6] += blo(r.w); va[7] += bhi(r.w); }

// ---------------- gather: mean-aggregate -> agg (bf16), 4 nodes/pack, 2-stage pipeline ------
// lane (g=lane>>3, j=lane&7): one instruction reads 8 neighbors' 16B chunks (1KB/instr).
// Rows for it+1 and indices for it+2 issue before consuming it -> 8 loads in flight/wave.
__global__ __launch_bounds__(256) void gather_kernel(
    const unsigned short* __restrict__ in, unsigned short* __restrict__ agg,
    const int* __restrict__ cnt, const int* __restrict__ bucket) {
    int tid = threadIdx.x;
    int lane = tid & 63;
    int g = lane >> 3, j = lane & 7;
    int wv = (blockIdx.x * blockDim.x + tid) >> 6;
    int nw = (gridDim.x * blockDim.x) >> 6;
    const int NQ = (N_NODES + 4) / 4;   // packs cover nodes 0..100003 (incl. sentinel N)

    for (int pr = wv; pr < NQ; pr += nw) {
        int n0 = pr * 4;
        int c[4], cc[4];
        const int* br[4];
        int nmax = 0;
#pragma unroll
        for (int i = 0; i < 4; ++i) {
            int nd = n0 + i;
            c[i] = (nd < N_NODES) ? cnt[nd] : 0;
            cc[i] = c[i] < CAP ? c[i] : CAP;
            br[i] = &bucket[(size_t)(nd < N_NODES ? nd : 0) * CAP];
            int ni = (cc[i] + 7) >> 3;
            nmax = ni > nmax ? ni : nmax;
        }
        float acc[4][8] = {};
        if (nmax > 0) {
            int inxt[4];
            uint4 rcur[4], rnxt[4];
#pragma unroll
            for (int i = 0; i < 4; ++i) inxt[i] = br[i][g];           // indices it=0
#pragma unroll
            for (int i = 0; i < 4; ++i) {                              // rows it=0
                int s = (g < cc[i]) ? inxt[i] : N_NODES;
                rcur[i] = *(const uint4*)&in[(size_t)s * D + j * 8];
            }
#pragma unroll
            for (int i = 0; i < 4; ++i) inxt[i] = br[i][8 + g];        // indices it=1
            for (int it = 0; it < nmax; ++it) {
                bool more = (it + 1 < nmax);                           // wave-uniform
                int inew[4];
                if (more) {
                    int slot1 = (it + 1) * 8 + g;
#pragma unroll
                    for (int i = 0; i < 4; ++i) {                      // rows it+1
                        int s = (slot1 < cc[i]) ? inxt[i] : N_NODES;
                        rnxt[i] = *(const uint4*)&in[(size_t)s * D + j * 8];
                    }
                    int slot2 = ((it + 2) * 8 + g) & (CAP - 1);        // wrap: masked later
#pragma unroll
                    for (int i = 0; i < 4; ++i) inew[i] = br[i][slot2]; // indices it+2
                }
#pragma unroll
                for (int i = 0; i < 4; ++i) ACC8(acc[i], rcur[i])      // consume it
                if (more) {
#pragma unroll
                    for (int i = 0; i < 4; ++i) { rcur[i] = rnxt[i]; inxt[i] = inew[i]; }
                }
            }
        }
        // butterfly-reduce across neighbor-groups g (lanes with equal j)
#pragma unroll
        for (int m = 8; m <= 32; m <<= 1)
#pragma unroll
            for (int i = 0; i < 4; ++i)
#pragma unroll
                for (int k = 0; k < 8; ++k)
                    acc[i][k] += __shfl_xor(acc[i][k], m, 64);
        // lane group g==i writes node n0+i (8 lanes x uint4 = 128B row)
#pragma unroll
        for (int i = 0; i < 4; ++i) {
            int nd = n0 + i;
            if (g == i && nd <= N_NODES) {
                float dinv = 1.0f / (float)(c[i] > 0 ? c[i] : 1);
                uint4 pk;
                pk.x = (unsigned)f2bf(acc[i][0] * dinv) | ((unsigned)f2bf(acc[i][1] * dinv) << 16);
                pk.y = (unsigned)f2bf(acc[i][2] * dinv) | ((unsigned)f2bf(acc[i][3] * dinv) << 16);
                pk.z = (unsigned)f2bf(acc[i][4] * dinv) | ((unsigned)f2bf(acc[i][5] * dinv) << 16);
                pk.w = (unsigned)f2bf(acc[i][6] * dinv) | ((unsigned)f2bf(acc[i][7] * dinv) << 16);
                *(uint4*)&agg[(size_t)nd * D + j * 8] = pk;
            }
        }
    }
}

// ---------------- dense hidden GEMM: C = relu([agg|x] @ Wcat + b), 64-node tile ----------------
__global__ __launch_bounds__(256) void gemm_hidden_kernel(
    const unsigned short* __restrict__ agg, const unsigned short* __restrict__ xin,
    unsigned short* __restrict__ out, const unsigned short* __restrict__ Wt_g,
    const float* __restrict__ bias_v) {
    __shared__ __align__(16) unsigned short Wt[64 * APAD];
    int tid = threadIdx.x;
#pragma unroll
    for (int i = 0; i < 4; ++i) {
        int e = (tid + i * 256) * 8;
        uint4 v = *(const uint4*)&Wt_g[e];
        *(uint4*)&Wt[(e >> 7) * APAD + (e & 127)] = v;
    }
    __syncthreads();

    int lane = tid & 63, w = tid >> 6;
    int r16 = lane & 15, g4 = lane >> 4;
    int base = blockIdx.x * 64;
    int arow = base + w * 16 + r16;
    int nd = arow < N_NODES ? arow : N_NODES;   // clamp to sentinel zero row

    f32x4 acc[4] = {{0.f,0.f,0.f,0.f},{0.f,0.f,0.f,0.f},{0.f,0.f,0.f,0.f},{0.f,0.f,0.f,0.f}};
#pragma unroll
    for (int ks = 0; ks < 4; ++ks) {
        int koff = ks * 32 + g4 * 8;
        short8 a;
        if (ks < 2) a = *(const short8*)&agg[(size_t)nd * D + koff];
        else        a = *(const short8*)&xin[(size_t)nd * D + (koff - 64)];
#pragma unroll
        for (int n = 0; n < 4; ++n) {
            short8 b = *(const short8*)&Wt[(n * 16 + r16) * APAD + koff];
            acc[n] = __builtin_amdgcn_mfma_f32_16x16x32_bf16(a, b, acc[n], 0, 0, 0);
        }
    }
#pragma unroll
    for (int n = 0; n < 4; ++n) {
        int col = n * 16 + r16;
        float bias = bias_v[col];
#pragma unroll
        for (int r = 0; r < 4; ++r) {
            int node = base + w * 16 + g4 * 4 + r;
            if (node <= N_NODES) {   // row N: keep sentinel zero (bias must not leak in)
                float v = node < N_NODES ? fmaxf(acc[n][r] + bias, 0.f) : 0.f;
                out[(size_t)node * D + col] = f2bf(v);
            }
        }
    }
}

// ---------------- output GEMM (64->10) + fused log_softmax ----------------
__global__ __launch_bounds__(256) void gemm_out_kernel(
    const unsigned short* __restrict__ agg, const unsigned short* __restrict__ xin,
    float* __restrict__ out, const unsigned short* __restrict__ Wt_g,
    const float* __restrict__ bias_v) {
    __shared__ __align__(16) unsigned short Wt[16 * APAD];
    int tid = threadIdx.x;
    {
        int e = tid * 8;
        uint4 v = *(const uint4*)&Wt_g[e];
        *(uint4*)&Wt[(e >> 7) * APAD + (e & 127)] = v;
    }
    __syncthreads();

    int lane = tid & 63, w = tid >> 6;
    int r16 = lane & 15, g4 = lane >> 4;
    int base = blockIdx.x * 64;
    int arow = base + w * 16 + r16;
    int nd = arow < N_NODES ? arow : N_NODES;

    f32x4 acc = {0.f, 0.f, 0.f, 0.f};
#pragma unroll
    for (int ks = 0; ks < 4; ++ks) {
        int koff = ks * 32 + g4 * 8;
        short8 a;
        if (ks < 2) a = *(const short8*)&agg[(size_t)nd * D + koff];
        else        a = *(const short8*)&xin[(size_t)nd * D + (koff - 64)];
        short8 b = *(const short8*)&Wt[r16 * APAD + koff];
        acc = __builtin_amdgcn_mfma_f32_16x16x32_bf16(a, b, acc, 0, 0, 0);
    }
    float bias = r16 < DOUT ? bias_v[r16] : -1e30f;   // pad cols -> exp()=0
#pragma unroll
    for (int r = 0; r < 4; ++r) {
        float v = acc[r] + bias;
        float m = v;
        m = fmaxf(m, __shfl_xor(m, 1, 16));
        m = fmaxf(m, __shfl_xor(m, 2, 16));
        m = fmaxf(m, __shfl_xor(m, 4, 16));
        m = fmaxf(m, __shfl_xor(m, 8, 16));
        float e = expf(v - m);
        float s = e;
        s += __shfl_xor(s, 1, 16);
        s += __shfl_xor(s, 2, 16);
        s += __shfl_xor(s, 4, 16);
        s += __shfl_xor(s, 8, 16);
        int node = base + w * 16 + g4 * 4 + r;
        if (node < N_NODES && r16 < DOUT)
            out[(size_t)node * DOUT + r16] = v - m - logf(s);
    }
}

extern "C" void kernel_launch(void* const* d_in, const int* in_sizes, int n_in,
                              void* d_out, int out_size, void* d_ws, size_t ws_size,
                              hipStream_t stream) {
    const float* x       = (const float*)d_in[0];
    const int*   ei      = (const int*)d_in[1];
    const int*   src     = ei;            // edge_index[0]
    const int*   dst     = ei + N_EDGES;  // edge_index[1]
    const float* W_out0  = (const float*)d_in[2];
    const float* b0      = (const float*)d_in[3];
    const float* W_root0 = (const float*)d_in[4];
    const float* W_out1  = (const float*)d_in[5];
    const float* b1      = (const float*)d_in[6];
    const float* W_root1 = (const float*)d_in[7];
    const float* W_out2  = (const float*)d_in[8];
    const float* b2      = (const float*)d_in[9];
    const float* W_root2 = (const float*)d_in[10];
    float* outp = (float*)d_out;

    // ws: xb | h0 | h1 ((N+1)*64 bf16 each; agg scratch rotates through the free one)
    //     | Wt0 | Wt1 (8192) | Wt2 (2048) | cnt (N i32) | bucket (N*64 i32)   ~64.4 MB
    const size_t ROWS = (size_t)(N_NODES + 1) * D;
    unsigned short* xb  = (unsigned short*)d_ws;
    unsigned short* h0  = xb + ROWS;
    unsigned short* h1  = h0 + ROWS;
    unsigned short* Wt0 = h1 + ROWS;
    unsigned short* Wt1 = Wt0 + 8192;
    unsigned short* Wt2 = Wt1 + 8192;
    int* cnt    = (int*)(Wt2 + 2048);
    int* bucket = cnt + N_NODES;

    hipMemsetAsync(cnt, 0, N_NODES * sizeof(int), stream);
    // 1024 blocks = 128 per XCD-group; each group scans the full edge list
    fill_kernel<<<1024, 256, 0, stream>>>(src, dst, cnt, bucket);
    cvt_kernel<<<((N_NODES + 1) * D / 4 + 255) / 256, 256, 0, stream>>>(x, xb);
    prep_w_kernel<<<(16384 + 2048 + 255) / 256, 256, 0, stream>>>(
        W_out0, W_root0, W_out1, W_root1, W_out2, W_root2, Wt0, Wt1, Wt2);

    const int GB = 2048;                      // gather: grid-stride
    const int tiles = (N_NODES + 63) / 64;    // 1563 GEMM tiles
    // layer 0: agg -> h1 (free), gemm -> h0
    gather_kernel<<<GB, 256, 0, stream>>>(xb, h1, cnt, bucket);
    gemm_hidden_kernel<<<tiles, 256, 0, stream>>>(h1, xb, h0, Wt0, b0);
    // layer 1: agg -> xb (free), gemm -> h1
    gather_kernel<<<GB, 256, 0, stream>>>(h0, xb, cnt, bucket);
    gemm_hidden_kernel<<<tiles, 256, 0, stream>>>(xb, h0, h1, Wt1, b1);
    // layer 2: agg -> h0 (free), gemm -> out
    gather_kernel<<<GB, 256, 0, stream>>>(h1, h0, cnt, bucket);
    gemm_out_kernel<<<tiles, 256, 0, stream>>>(h0, h1, outp, Wt2, b2);
}

// Round 9
// 298.114 us; speedup vs baseline: 2.2576x; 1.1715x over previous
//
#include <hip/hip_runtime.h>
#include <hip/hip_bf16.h>
#include <math.h>

#define N_NODES 100000
#define N_EDGES 1600000
#define D 64
#define DOUT 10
#define CAP 64
#define APAD 136     // LDS row stride (bf16): 272B, 16B-aligned
#define NBIN 782     // ceil(N/128) dst-bins
#define ABLK 128     // pass-A blocks
#define ACHUNK 12500 // edges per pass-A block (128*12500 = 1.6M exactly)
#define SCAP 48      // per-(block,bin) segment capacity: mean 16, +8 sigma

typedef __attribute__((ext_vector_type(8))) short short8;
typedef __attribute__((ext_vector_type(4))) float f32x4;

__device__ __forceinline__ unsigned short f2bf(float f) {
    __hip_bfloat16 h = __float2bfloat16(f);
    return __builtin_bit_cast(unsigned short, h);
}
__device__ __forceinline__ float blo(unsigned v) { return __builtin_bit_cast(float, v << 16); }
__device__ __forceinline__ float bhi(unsigned v) { return __builtin_bit_cast(float, v & 0xFFFF0000u); }

// ---------------- pass A: chunk -> per-(block,bin) packed segments; zero global atomics -----
__global__ __launch_bounds__(256) void partA_kernel(const int* __restrict__ src,
                                                    const int* __restrict__ dst,
                                                    int* __restrict__ ebuf,
                                                    int* __restrict__ counts) {
    __shared__ int hist[NBIN];
    int tid = threadIdx.x;
    int blk = blockIdx.x;
    for (int i = tid; i < NBIN; i += 256) hist[i] = 0;
    __syncthreads();
    int e0 = blk * ACHUNK;
    for (int e = e0 + tid; e < e0 + ACHUNK; e += 256) {
        int d = dst[e];
        int s = src[e];
        int bin = d >> 7;
        int r = atomicAdd(&hist[bin], 1);            // LDS atomic
        if (r < SCAP) ebuf[(blk * NBIN + bin) * SCAP + r] = (s << 7) | (d & 127);
    }
    __syncthreads();
    for (int i = tid; i < NBIN; i += 256) {
        int h = hist[i];
        counts[blk * NBIN + i] = h < SCAP ? h : SCAP;
    }
}

// ---------------- pass B: per-bin compaction -> bucket slab + true cnt, coalesced out -------
__global__ __launch_bounds__(256) void partB_kernel(const int* __restrict__ ebuf,
                                                    const int* __restrict__ counts,
                                                    int* __restrict__ cnt,
                                                    int* __restrict__ bucket) {
    __shared__ int lb[128 * CAP];   // 32 KB
    __shared__ int lcnt[128];
    __shared__ int sc[ABLK];
    int tid = threadIdx.x;
    int bin = blockIdx.x;
    for (int i = tid; i < 128 * CAP; i += 256) lb[i] = N_NODES;  // sentinel -> zero row
    if (tid < 128) lcnt[tid] = 0;
    if (tid < ABLK) sc[tid] = counts[tid * NBIN + bin];
    __syncthreads();
    for (int i = tid; i < ABLK * SCAP; i += 256) {
        int seg = i / SCAP;
        int slot = i - seg * SCAP;
        if (slot < sc[seg]) {
            int v = ebuf[(seg * NBIN + bin) * SCAP + slot];
            int dloc = v & 127;
            int p = atomicAdd(&lcnt[dloc], 1);        // LDS atomic; true in-degree
            if (p < CAP) lb[dloc * CAP + p] = v >> 7;
        }
    }
    __syncthreads();
    size_t nodeBase = (size_t)bin << 7;
    int lastNode = N_NODES - (int)nodeBase;           // valid dloc < lastNode
    for (int i = tid; i < 128 * CAP / 4; i += 256) {
        int dloc = (i * 4) >> 6;
        if (dloc < lastNode)
            *(int4*)&bucket[nodeBase * CAP + i * 4] = *(const int4*)&lb[i * 4];
    }
    if (tid < 128 && tid < lastNode) cnt[nodeBase + tid] = lcnt[tid];
}

// ---------------- x (f32) -> xb (bf16), plus zero sentinel row N ----------------
__global__ void cvt_kernel(const float* __restrict__ x, unsigned short* __restrict__ xb) {
    int i = blockIdx.x * blockDim.x + threadIdx.x;
    const int total = (N_NODES + 1) * D / 4;
    if (i >= total) return;
    ushort4 o;
    if (i * 4 < N_NODES * D) {
        float4 v = *(const float4*)&x[i * 4];
        o.x = f2bf(v.x); o.y = f2bf(v.y); o.z = f2bf(v.z); o.w = f2bf(v.w);
    } else {
        o.x = 0; o.y = 0; o.z = 0; o.w = 0;
    }
    *(ushort4*)&xb[i * 4] = o;
}

// --------- pre-transpose weights to Wt[col j][k] bf16 (k<64: W_out, k>=64: W_root) ---------
__global__ void prep_w_kernel(const float* __restrict__ W_out0, const float* __restrict__ W_root0,
                              const float* __restrict__ W_out1, const float* __restrict__ W_root1,
                              const float* __restrict__ W_out2, const float* __restrict__ W_root2,
                              unsigned short* __restrict__ Wt0, unsigned short* __restrict__ Wt1,
                              unsigned short* __restrict__ Wt2) {
    int idx = blockIdx.x * blockDim.x + threadIdx.x;
    if (idx < 8192) {
        int j = idx >> 7, k = idx & 127;
        float v = k < 64 ? W_out0[k * D + j] : W_root0[(k - 64) * D + j];
        Wt0[idx] = f2bf(v);
    } else if (idx < 16384) {
        int t = idx - 8192;
        int j = t >> 7, k = t & 127;
        float v = k < 64 ? W_out1[k * D + j] : W_root1[(k - 64) * D + j];
        Wt1[t] = f2bf(v);
    } else if (idx < 16384 + 2048) {
        int t = idx - 16384;
        int j = t >> 7, k = t & 127;
        float v = 0.f;
        if (j < DOUT) v = k < 64 ? W_out2[k * DOUT + j] : W_root2[(k - 64) * DOUT + j];
        Wt2[t] = f2bf(v);
    }
}

#define ACC8(va, r) { va[0] += blo(r.x); va[1] += bhi(r.x); va[2] += blo(r.y); va[3] += bhi(r.y); \
                      va[4] += blo(r.z); va[5] += bhi(r.z); va[6] += blo(r.w); va[7] += bhi(r.w); }

// ---------------- gather: mean-aggregate -> agg (bf16), 4 nodes/pack, 2-stage pipeline ------
__global__ __launch_bounds__(256) void gather_kernel(
    const unsigned short* __restrict__ in, unsigned short* __restrict__ agg,
    const int* __restrict__ cnt, const int* __restrict__ bucket) {
    int tid = threadIdx.x;
    int lane = tid & 63;
    int g = lane >> 3, j = lane & 7;
    int wv = (blockIdx.x * blockDim.x + tid) >> 6;
    int nw = (gridDim.x * blockDim.x) >> 6;
    const int NQ = (N_NODES + 4) / 4;   // packs cover nodes 0..100003 (incl. sentinel N)

    for (int pr = wv; pr < NQ; pr += nw) {
        int n0 = pr * 4;
        int c[4], cc[4];
        const int* br[4];
        int nmax = 0;
#pragma unroll
        for (int i = 0; i < 4; ++i) {
            int nd = n0 + i;
            c[i] = (nd < N_NODES) ? cnt[nd] : 0;
            cc[i] = c[i] < CAP ? c[i] : CAP;
            br[i] = &bucket[(size_t)(nd < N_NODES ? nd : 0) * CAP];
            int ni = (cc[i] + 7) >> 3;
            nmax = ni > nmax ? ni : nmax;
        }
        float acc[4][8] = {};
        if (nmax > 0) {
            int inxt[4];
            uint4 rcur[4], rnxt[4];
#pragma unroll
            for (int i = 0; i < 4; ++i) inxt[i] = br[i][g];           // indices it=0
#pragma unroll
            for (int i = 0; i < 4; ++i) {                              // rows it=0
                int s = (g < cc[i]) ? inxt[i] : N_NODES;
                rcur[i] = *(const uint4*)&in[(size_t)s * D + j * 8];
            }
#pragma unroll
            for (int i = 0; i < 4; ++i) inxt[i] = br[i][8 + g];        // indices it=1
            for (int it = 0; it < nmax; ++it) {
                bool more = (it + 1 < nmax);                           // wave-uniform
                int inew[4];
                if (more) {
                    int slot1 = (it + 1) * 8 + g;
#pragma unroll
                    for (int i = 0; i < 4; ++i) {                      // rows it+1
                        int s = (slot1 < cc[i]) ? inxt[i] : N_NODES;
                        rnxt[i] = *(const uint4*)&in[(size_t)s * D + j * 8];
                    }
                    int slot2 = ((it + 2) * 8 + g) & (CAP - 1);        // wrap: masked later
#pragma unroll
                    for (int i = 0; i < 4; ++i) inew[i] = br[i][slot2]; // indices it+2
                }
#pragma unroll
                for (int i = 0; i < 4; ++i) ACC8(acc[i], rcur[i])      // consume it
                if (more) {
#pragma unroll
                    for (int i = 0; i < 4; ++i) { rcur[i] = rnxt[i]; inxt[i] = inew[i]; }
                }
            }
        }
        // butterfly-reduce across neighbor-groups g (lanes with equal j)
#pragma unroll
        for (int m = 8; m <= 32; m <<= 1)
#pragma unroll
            for (int i = 0; i < 4; ++i)
#pragma unroll
                for (int k = 0; k < 8; ++k)
                    acc[i][k] += __shfl_xor(acc[i][k], m, 64);
        // lane group g==i writes node n0+i (8 lanes x uint4 = 128B row)
#pragma unroll
        for (int i = 0; i < 4; ++i) {
            int nd = n0 + i;
            if (g == i && nd <= N_NODES) {
                float dinv = 1.0f / (float)(c[i] > 0 ? c[i] : 1);
                uint4 pk;
                pk.x = (unsigned)f2bf(acc[i][0] * dinv) | ((unsigned)f2bf(acc[i][1] * dinv) << 16);
                pk.y = (unsigned)f2bf(acc[i][2] * dinv) | ((unsigned)f2bf(acc[i][3] * dinv) << 16);
                pk.z = (unsigned)f2bf(acc[i][4] * dinv) | ((unsigned)f2bf(acc[i][5] * dinv) << 16);
                pk.w = (unsigned)f2bf(acc[i][6] * dinv) | ((unsigned)f2bf(acc[i][7] * dinv) << 16);
                *(uint4*)&agg[(size_t)nd * D + j * 8] = pk;
            }
        }
    }
}

// ---------------- dense hidden GEMM: C = relu([agg|x] @ Wcat + b), 64-node tile ----------------
__global__ __launch_bounds__(256) void gemm_hidden_kernel(
    const unsigned short* __restrict__ agg, const unsigned short* __restrict__ xin,
    unsigned short* __restrict__ out, const unsigned short* __restrict__ Wt_g,
    const float* __restrict__ bias_v) {
    __shared__ __align__(16) unsigned short Wt[64 * APAD];
    int tid = threadIdx.x;
#pragma unroll
    for (int i = 0; i < 4; ++i) {
        int e = (tid + i * 256) * 8;
        uint4 v = *(const uint4*)&Wt_g[e];
        *(uint4*)&Wt[(e >> 7) * APAD + (e & 127)] = v;
    }
    __syncthreads();

    int lane = tid & 63, w = tid >> 6;
    int r16 = lane & 15, g4 = lane >> 4;
    int base = blockIdx.x * 64;
    int arow = base + w * 16 + r16;
    int nd = arow < N_NODES ? arow : N_NODES;   // clamp to sentinel zero row

    f32x4 acc[4] = {{0.f,0.f,0.f,0.f},{0.f,0.f,0.f,0.f},{0.f,0.f,0.f,0.f},{0.f,0.f,0.f,0.f}};
#pragma unroll
    for (int ks = 0; ks < 4; ++ks) {
        int koff = ks * 32 + g4 * 8;
        short8 a;
        if (ks < 2) a = *(const short8*)&agg[(size_t)nd * D + koff];
        else        a = *(const short8*)&xin[(size_t)nd * D + (koff - 64)];
#pragma unroll
        for (int n = 0; n < 4; ++n) {
            short8 b = *(const short8*)&Wt[(n * 16 + r16) * APAD + koff];
            acc[n] = __builtin_amdgcn_mfma_f32_16x16x32_bf16(a, b, acc[n], 0, 0, 0);
        }
    }
#pragma unroll
    for (int n = 0; n < 4; ++n) {
        int col = n * 16 + r16;
        float bias = bias_v[col];
#pragma unroll
        for (int r = 0; r < 4; ++r) {
            int node = base + w * 16 + g4 * 4 + r;
            if (node <= N_NODES) {   // row N: keep sentinel zero (bias must not leak in)
                float v = node < N_NODES ? fmaxf(acc[n][r] + bias, 0.f) : 0.f;
                out[(size_t)node * D + col] = f2bf(v);
            }
        }
    }
}

// ---------------- output GEMM (64->10) + fused log_softmax ----------------
__global__ __launch_bounds__(256) void gemm_out_kernel(
    const unsigned short* __restrict__ agg, const unsigned short* __restrict__ xin,
    float* __restrict__ out, const unsigned short* __restrict__ Wt_g,
    const float* __restrict__ bias_v) {
    __shared__ __align__(16) unsigned short Wt[16 * APAD];
    int tid = threadIdx.x;
    {
        int e = tid * 8;
        uint4 v = *(const uint4*)&Wt_g[e];
        *(uint4*)&Wt[(e >> 7) * APAD + (e & 127)] = v;
    }
    __syncthreads();

    int lane = tid & 63, w = tid >> 6;
    int r16 = lane & 15, g4 = lane >> 4;
    int base = blockIdx.x * 64;
    int arow = base + w * 16 + r16;
    int nd = arow < N_NODES ? arow : N_NODES;

    f32x4 acc = {0.f, 0.f, 0.f, 0.f};
#pragma unroll
    for (int ks = 0; ks < 4; ++ks) {
        int koff = ks * 32 + g4 * 8;
        short8 a;
        if (ks < 2) a = *(const short8*)&agg[(size_t)nd * D + koff];
        else        a = *(const short8*)&xin[(size_t)nd * D + (koff - 64)];
        short8 b = *(const short8*)&Wt[r16 * APAD + koff];
        acc = __builtin_amdgcn_mfma_f32_16x16x32_bf16(a, b, acc, 0, 0, 0);
    }
    float bias = r16 < DOUT ? bias_v[r16] : -1e30f;   // pad cols -> exp()=0
#pragma unroll
    for (int r = 0; r < 4; ++r) {
        float v = acc[r] + bias;
        float m = v;
        m = fmaxf(m, __shfl_xor(m, 1, 16));
        m = fmaxf(m, __shfl_xor(m, 2, 16));
        m = fmaxf(m, __shfl_xor(m, 4, 16));
        m = fmaxf(m, __shfl_xor(m, 8, 16));
        float e = expf(v - m);
        float s = e;
        s += __shfl_xor(s, 1, 16);
        s += __shfl_xor(s, 2, 16);
        s += __shfl_xor(s, 4, 16);
        s += __shfl_xor(s, 8, 16);
        int node = base + w * 16 + g4 * 4 + r;
        if (node < N_NODES && r16 < DOUT)
            out[(size_t)node * DOUT + r16] = v - m - logf(s);
    }
}

extern "C" void kernel_launch(void* const* d_in, const int* in_sizes, int n_in,
                              void* d_out, int out_size, void* d_ws, size_t ws_size,
                              hipStream_t stream) {
    const float* x       = (const float*)d_in[0];
    const int*   ei      = (const int*)d_in[1];
    const int*   src     = ei;            // edge_index[0]
    const int*   dst     = ei + N_EDGES;  // edge_index[1]
    const float* W_out0  = (const float*)d_in[2];
    const float* b0      = (const float*)d_in[3];
    const float* W_root0 = (const float*)d_in[4];
    const float* W_out1  = (const float*)d_in[5];
    const float* b1      = (const float*)d_in[6];
    const float* W_root1 = (const float*)d_in[7];
    const float* W_out2  = (const float*)d_in[8];
    const float* b2      = (const float*)d_in[9];
    const float* W_root2 = (const float*)d_in[10];
    float* outp = (float*)d_out;

    // ws: xb | h0 | h1 ((N+1)*64 bf16) | Wt0|Wt1 (8192) | Wt2 (2048) | cnt (N i32)
    //     | bucket (N*64 i32)   ~64.5 MB. ebuf/counts ALIAS h0+h1 (dead until gather0).
    const size_t ROWS = (size_t)(N_NODES + 1) * D;
    unsigned short* xb  = (unsigned short*)d_ws;
    unsigned short* h0  = xb + ROWS;
    unsigned short* h1  = h0 + ROWS;
    unsigned short* Wt0 = h1 + ROWS;
    unsigned short* Wt1 = Wt0 + 8192;
    unsigned short* Wt2 = Wt1 + 8192;
    int* cnt    = (int*)(Wt2 + 2048);
    int* bucket = cnt + N_NODES;
    int* ebuf   = (int*)h0;                     // 128*782*48 ints = 19.2 MB < 25.6 MB
    int* counts = ebuf + ABLK * NBIN * SCAP;    // 400 KB, still inside h0+h1

    partA_kernel<<<ABLK, 256, 0, stream>>>(src, dst, ebuf, counts);
    partB_kernel<<<NBIN, 256, 0, stream>>>(ebuf, counts, cnt, bucket);
    cvt_kernel<<<((N_NODES + 1) * D / 4 + 255) / 256, 256, 0, stream>>>(x, xb);
    prep_w_kernel<<<(16384 + 2048 + 255) / 256, 256, 0, stream>>>(
        W_out0, W_root0, W_out1, W_root1, W_out2, W_root2, Wt0, Wt1, Wt2);

    const int GB = 2048;                      // gather: grid-stride
    const int tiles = (N_NODES + 63) / 64;    // 1563 GEMM tiles
    // layer 0: agg -> h1 (free; ebuf dead after partB), gemm -> h0
    gather_kernel<<<GB, 256, 0, stream>>>(xb, h1, cnt, bucket);
    gemm_hidden_kernel<<<tiles, 256, 0, stream>>>(h1, xb, h0, Wt0, b0);
    // layer 1: agg -> xb (free), gemm -> h1
    gather_kernel<<<GB, 256, 0, stream>>>(h0, xb, cnt, bucket);
    gemm_hidden_kernel<<<tiles, 256, 0, stream>>>(xb, h0, h1, Wt1, b1);
    // layer 2: agg -> h0 (free), gemm -> out
    gather_kernel<<<GB, 256, 0, stream>>>(h1, h0, cnt, bucket);
    gemm_out_kernel<<<tiles, 256, 0, stream>>>(h0, h1, outp, Wt2, b2);
}

// Round 10
// 275.444 us; speedup vs baseline: 2.4434x; 1.0823x over previous
//
#include <hip/hip_runtime.h>
#include <hip/hip_bf16.h>
#include <math.h>

#define N_NODES 100000
#define N_EDGES 1600000
#define D 64
#define DOUT 10
#define CAP 64
#define APAD 136     // LDS row stride (bf16): 272B, 16B-aligned
#define NBIN 782     // ceil(N/128) dst-bins
#define ABLK 256     // pass-A blocks
#define ACHUNK 6272  // edges per pass-A block (4-aligned; 256*6272 covers 1.6M w/ guard)
#define SCAP 32      // per-(block,bin) segment capacity: mean 8, P(>32) ~ 1e-11

typedef __attribute__((ext_vector_type(8))) short short8;
typedef __attribute__((ext_vector_type(4))) float f32x4;

__device__ __forceinline__ unsigned short f2bf(float f) {
    __hip_bfloat16 h = __float2bfloat16(f);
    return __builtin_bit_cast(unsigned short, h);
}
__device__ __forceinline__ float blo(unsigned v) { return __builtin_bit_cast(float, v << 16); }
__device__ __forceinline__ float bhi(unsigned v) { return __builtin_bit_cast(float, v & 0xFFFF0000u); }

// ---------------- pass A: chunk -> per-(block,bin) packed segments; zero global atomics -----
// 1024 threads (16 waves/CU) + int4 edge loads: latency hidden, unlike r9's 1-wave/SIMD.
#define PROCE(dv, sv) { int bin = (dv) >> 7; int r = atomicAdd(&hist[bin], 1); \
    if (r < SCAP) ebuf[((size_t)blk * NBIN + bin) * SCAP + r] = ((sv) << 7) | ((dv) & 127); }

__global__ __launch_bounds__(1024) void partA_kernel(const int* __restrict__ src,
                                                     const int* __restrict__ dst,
                                                     int* __restrict__ ebuf,
                                                     int* __restrict__ counts) {
    __shared__ int hist[NBIN];
    int tid = threadIdx.x;
    int blk = blockIdx.x;
    for (int i = tid; i < NBIN; i += 1024) hist[i] = 0;
    __syncthreads();
    int e0 = blk * ACHUNK;
    for (int b = tid; b < ACHUNK / 4; b += 1024) {
        int e = e0 + b * 4;
        if (e + 4 <= N_EDGES) {
            int4 d4 = *(const int4*)&dst[e];
            int4 s4 = *(const int4*)&src[e];
            PROCE(d4.x, s4.x) PROCE(d4.y, s4.y) PROCE(d4.z, s4.z) PROCE(d4.w, s4.w)
        } else {
            for (int k = 0; e + k < N_EDGES && k < 4; ++k) {
                int dv = dst[e + k], sv = src[e + k];
                PROCE(dv, sv)
            }
        }
    }
    __syncthreads();
    for (int i = tid; i < NBIN; i += 1024) {
        int h = hist[i];
        counts[blk * NBIN + i] = h < SCAP ? h : SCAP;
    }
}

// ---------------- pass B: per-bin compaction -> bucket slab + true cnt, coalesced out -------
__global__ __launch_bounds__(256) void partB_kernel(const int* __restrict__ ebuf,
                                                    const int* __restrict__ counts,
                                                    int* __restrict__ cnt,
                                                    int* __restrict__ bucket) {
    __shared__ int lb[128 * CAP];   // 32 KB
    __shared__ int lcnt[128];
    __shared__ int sc[ABLK];
    int tid = threadIdx.x;
    int bin = blockIdx.x;
    for (int i = tid; i < 128 * CAP; i += 256) lb[i] = N_NODES;  // sentinel -> zero row
    if (tid < 128) lcnt[tid] = 0;
    if (tid < ABLK) sc[tid] = counts[tid * NBIN + bin];
    __syncthreads();
    for (int i = tid; i < ABLK * SCAP; i += 256) {
        int seg = i >> 5;              // / SCAP
        int slot = i & (SCAP - 1);
        if (slot < sc[seg]) {
            int v = ebuf[((size_t)seg * NBIN + bin) * SCAP + slot];
            int dloc = v & 127;
            int p = atomicAdd(&lcnt[dloc], 1);        // LDS atomic; true in-degree
            if (p < CAP) lb[dloc * CAP + p] = v >> 7;
        }
    }
    __syncthreads();
    size_t nodeBase = (size_t)bin << 7;
    int lastNode = N_NODES - (int)nodeBase;           // valid dloc < lastNode
    for (int i = tid; i < 128 * CAP / 4; i += 256) {
        int dloc = (i * 4) >> 6;
        if (dloc < lastNode)
            *(int4*)&bucket[nodeBase * CAP + i * 4] = *(const int4*)&lb[i * 4];
    }
    if (tid < 128 && tid < lastNode) cnt[nodeBase + tid] = lcnt[tid];
}

// ---------------- x (f32) -> xb (bf16), plus zero sentinel row N ----------------
__global__ void cvt_kernel(const float* __restrict__ x, unsigned short* __restrict__ xb) {
    int i = blockIdx.x * blockDim.x + threadIdx.x;
    const int total = (N_NODES + 1) * D / 4;
    if (i >= total) return;
    ushort4 o;
    if (i * 4 < N_NODES * D) {
        float4 v = *(const float4*)&x[i * 4];
        o.x = f2bf(v.x); o.y = f2bf(v.y); o.z = f2bf(v.z); o.w = f2bf(v.w);
    } else {
        o.x = 0; o.y = 0; o.z = 0; o.w = 0;
    }
    *(ushort4*)&xb[i * 4] = o;
}

// --------- pre-transpose weights to Wt[col j][k] bf16 (k<64: W_out, k>=64: W_root) ---------
__global__ void prep_w_kernel(const float* __restrict__ W_out0, const float* __restrict__ W_root0,
                              const float* __restrict__ W_out1, const float* __restrict__ W_root1,
                              const float* __restrict__ W_out2, const float* __restrict__ W_root2,
                              unsigned short* __restrict__ Wt0, unsigned short* __restrict__ Wt1,
                              unsigned short* __restrict__ Wt2) {
    int idx = blockIdx.x * blockDim.x + threadIdx.x;
    if (idx < 8192) {
        int j = idx >> 7, k = idx & 127;
        float v = k < 64 ? W_out0[k * D + j] : W_root0[(k - 64) * D + j];
        Wt0[idx] = f2bf(v);
    } else if (idx < 16384) {
        int t = idx - 8192;
        int j = t >> 7, k = t & 127;
        float v = k < 64 ? W_out1[k * D + j] : W_root1[(k - 64) * D + j];
        Wt1[t] = f2bf(v);
    } else if (idx < 16384 + 2048) {
        int t = idx - 16384;
        int j = t >> 7, k = t & 127;
        float v = 0.f;
        if (j < DOUT) v = k < 64 ? W_out2[k * DOUT + j] : W_root2[(k - 64) * DOUT + j];
        Wt2[t] = f2bf(v);
    }
}

// ---------------- gather: 1 node per 8-lane group, 8 nodes/wave; no cross-group reduce ------
// Group g handles node n0+g; its 8 lanes (j) load that node's neighbor row (8x16B = full
// 128B row, coalesced; 8 groups = 1KB/instr). Depth-3 row pipeline hides L2/L3 latency.
// Divergent per-group trip count self-masks; no sentinel row loads, no butterfly, pack
// phase uses all 64 lanes.
__global__ __launch_bounds__(256) void gather_kernel(
    const unsigned short* __restrict__ in, unsigned short* __restrict__ agg,
    const int* __restrict__ cnt, const int* __restrict__ bucket) {
    int tid = threadIdx.x;
    int lane = tid & 63;
    int g = lane >> 3, j = lane & 7;
    int wv = (blockIdx.x * blockDim.x + tid) >> 6;
    int nw = (gridDim.x * blockDim.x) >> 6;
    const int NP = (N_NODES + 8) / 8;   // 12501 packs cover nodes 0..100007

    for (int pr = wv; pr < NP; pr += nw) {
        int n0 = pr * 8;
        int nd = n0 + g;
        int node = nd < N_NODES ? nd : 0;
        int c = nd < N_NODES ? cnt[nd] : 0;
        int cc = c < CAP ? c : CAP;
        const int* __restrict__ brow = &bucket[(size_t)node * CAP];

        float a0 = 0.f, a1 = 0.f, a2 = 0.f, a3 = 0.f,
              a4 = 0.f, a5 = 0.f, a6 = 0.f, a7 = 0.f;
        uint4 rA = {0, 0, 0, 0}, rB = {0, 0, 0, 0}, rC = {0, 0, 0, 0};
        if (cc > 0) rA = *(const uint4*)&in[(size_t)brow[0] * D + j * 8];
        if (cc > 1) rB = *(const uint4*)&in[(size_t)brow[1] * D + j * 8];
        if (cc > 2) rC = *(const uint4*)&in[(size_t)brow[2] * D + j * 8];
        for (int it = 0; it < cc; ++it) {
            uint4 r = rA;
            rA = rB; rB = rC;
            if (it + 3 < cc) rC = *(const uint4*)&in[(size_t)brow[it + 3] * D + j * 8];
            a0 += blo(r.x); a1 += bhi(r.x);
            a2 += blo(r.y); a3 += bhi(r.y);
            a4 += blo(r.z); a5 += bhi(r.z);
            a6 += blo(r.w); a7 += bhi(r.w);
        }
        if (nd <= N_NODES) {   // sentinel row N written as zeros (c=0 -> acc=0)
            float dinv = 1.0f / (float)(c > 0 ? c : 1);
            uint4 pk;
            pk.x = (unsigned)f2bf(a0 * dinv) | ((unsigned)f2bf(a1 * dinv) << 16);
            pk.y = (unsigned)f2bf(a2 * dinv) | ((unsigned)f2bf(a3 * dinv) << 16);
            pk.z = (unsigned)f2bf(a4 * dinv) | ((unsigned)f2bf(a5 * dinv) << 16);
            pk.w = (unsigned)f2bf(a6 * dinv) | ((unsigned)f2bf(a7 * dinv) << 16);
            *(uint4*)&agg[(size_t)nd * D + j * 8] = pk;
        }
    }
}

// ---------------- dense hidden GEMM: C = relu([agg|x] @ Wcat + b), 64-node tile ----------------
__global__ __launch_bounds__(256) void gemm_hidden_kernel(
    const unsigned short* __restrict__ agg, const unsigned short* __restrict__ xin,
    unsigned short* __restrict__ out, const unsigned short* __restrict__ Wt_g,
    const float* __restrict__ bias_v) {
    __shared__ __align__(16) unsigned short Wt[64 * APAD];
    int tid = threadIdx.x;
#pragma unroll
    for (int i = 0; i < 4; ++i) {
        int e = (tid + i * 256) * 8;
        uint4 v = *(const uint4*)&Wt_g[e];
        *(uint4*)&Wt[(e >> 7) * APAD + (e & 127)] = v;
    }
    __syncthreads();

    int lane = tid & 63, w = tid >> 6;
    int r16 = lane & 15, g4 = lane >> 4;
    int base = blockIdx.x * 64;
    int arow = base + w * 16 + r16;
    int nd = arow < N_NODES ? arow : N_NODES;   // clamp to sentinel zero row

    f32x4 acc[4] = {{0.f,0.f,0.f,0.f},{0.f,0.f,0.f,0.f},{0.f,0.f,0.f,0.f},{0.f,0.f,0.f,0.f}};
#pragma unroll
    for (int ks = 0; ks < 4; ++ks) {
        int koff = ks * 32 + g4 * 8;
        short8 a;
        if (ks < 2) a = *(const short8*)&agg[(size_t)nd * D + koff];
        else        a = *(const short8*)&xin[(size_t)nd * D + (koff - 64)];
#pragma unroll
        for (int n = 0; n < 4; ++n) {
            short8 b = *(const short8*)&Wt[(n * 16 + r16) * APAD + koff];
            acc[n] = __builtin_amdgcn_mfma_f32_16x16x32_bf16(a, b, acc[n], 0, 0, 0);
        }
    }
#pragma unroll
    for (int n = 0; n < 4; ++n) {
        int col = n * 16 + r16;
        float bias = bias_v[col];
#pragma unroll
        for (int r = 0; r < 4; ++r) {
            int node = base + w * 16 + g4 * 4 + r;
            if (node <= N_NODES) {   // row N: keep sentinel zero (bias must not leak in)
                float v = node < N_NODES ? fmaxf(acc[n][r] + bias, 0.f) : 0.f;
                out[(size_t)node * D + col] = f2bf(v);
            }
        }
    }
}

// ---------------- output GEMM (64->10) + fused log_softmax ----------------
__global__ __launch_bounds__(256) void gemm_out_kernel(
    const unsigned short* __restrict__ agg, const unsigned short* __restrict__ xin,
    float* __restrict__ out, const unsigned short* __restrict__ Wt_g,
    const float* __restrict__ bias_v) {
    __shared__ __align__(16) unsigned short Wt[16 * APAD];
    int tid = threadIdx.x;
    {
        int e = tid * 8;
        uint4 v = *(const uint4*)&Wt_g[e];
        *(uint4*)&Wt[(e >> 7) * APAD + (e & 127)] = v;
    }
    __syncthreads();

    int lane = tid & 63, w = tid >> 6;
    int r16 = lane & 15, g4 = lane >> 4;
    int base = blockIdx.x * 64;
    int arow = base + w * 16 + r16;
    int nd = arow < N_NODES ? arow : N_NODES;

    f32x4 acc = {0.f, 0.f, 0.f, 0.f};
#pragma unroll
    for (int ks = 0; ks < 4; ++ks) {
        int koff = ks * 32 + g4 * 8;
        short8 a;
        if (ks < 2) a = *(const short8*)&agg[(size_t)nd * D + koff];
        else        a = *(const short8*)&xin[(size_t)nd * D + (koff - 64)];
        short8 b = *(const short8*)&Wt[r16 * APAD + koff];
        acc = __builtin_amdgcn_mfma_f32_16x16x32_bf16(a, b, acc, 0, 0, 0);
    }
    float bias = r16 < DOUT ? bias_v[r16] : -1e30f;   // pad cols -> exp()=0
#pragma unroll
    for (int r = 0; r < 4; ++r) {
        float v = acc[r] + bias;
        float m = v;
        m = fmaxf(m, __shfl_xor(m, 1, 16));
        m = fmaxf(m, __shfl_xor(m, 2, 16));
        m = fmaxf(m, __shfl_xor(m, 4, 16));
        m = fmaxf(m, __shfl_xor(m, 8, 16));
        float e = expf(v - m);
        float s = e;
        s += __shfl_xor(s, 1, 16);
        s += __shfl_xor(s, 2, 16);
        s += __shfl_xor(s, 4, 16);
        s += __shfl_xor(s, 8, 16);
        int node = base + w * 16 + g4 * 4 + r;
        if (node < N_NODES && r16 < DOUT)
            out[(size_t)node * DOUT + r16] = v - m - logf(s);
    }
}

extern "C" void kernel_launch(void* const* d_in, const int* in_sizes, int n_in,
                              void* d_out, int out_size, void* d_ws, size_t ws_size,
                              hipStream_t stream) {
    const float* x       = (const float*)d_in[0];
    const int*   ei      = (const int*)d_in[1];
    const int*   src     = ei;            // edge_index[0]
    const int*   dst     = ei + N_EDGES;  // edge_index[1]
    const float* W_out0  = (const float*)d_in[2];
    const float* b0      = (const float*)d_in[3];
    const float* W_root0 = (const float*)d_in[4];
    const float* W_out1  = (const float*)d_in[5];
    const float* b1      = (const float*)d_in[6];
    const float* W_root1 = (const float*)d_in[7];
    const float* W_out2  = (const float*)d_in[8];
    const float* b2      = (const float*)d_in[9];
    const float* W_root2 = (const float*)d_in[10];
    float* outp = (float*)d_out;

    // ws: xb | h0 | h1 ((N+1)*64 bf16) | Wt0|Wt1 (8192) | Wt2 (2048) | cnt (N i32)
    //     | bucket (N*64 i32)  ~64.5 MB.
    // ebuf (25.6 MB) + counts (0.8 MB) ALIAS the xb+h0+h1 pool (38.4 MB): dead after
    // partB, and cvt (writes xb) runs AFTER partB.
    const size_t ROWS = (size_t)(N_NODES + 1) * D;
    unsigned short* xb  = (unsigned short*)d_ws;
    unsigned short* h0  = xb + ROWS;
    unsigned short* h1  = h0 + ROWS;
    unsigned short* Wt0 = h1 + ROWS;
    unsigned short* Wt1 = Wt0 + 8192;
    unsigned short* Wt2 = Wt1 + 8192;
    int* cnt    = (int*)(Wt2 + 2048);
    int* bucket = cnt + N_NODES;
    int* ebuf   = (int*)d_ws;                        // 256*782*32 ints = 25.62 MB
    int* counts = ebuf + (size_t)ABLK * NBIN * SCAP; // 800 KB, still inside pool

    partA_kernel<<<ABLK, 1024, 0, stream>>>(src, dst, ebuf, counts);
    partB_kernel<<<NBIN, 256, 0, stream>>>(ebuf, counts, cnt, bucket);
    cvt_kernel<<<((N_NODES + 1) * D / 4 + 255) / 256, 256, 0, stream>>>(x, xb);
    prep_w_kernel<<<(16384 + 2048 + 255) / 256, 256, 0, stream>>>(
        W_out0, W_root0, W_out1, W_root1, W_out2, W_root2, Wt0, Wt1, Wt2);

    const int GB = 1563;                      // 6252 waves -> exactly 2 packs/wave
    const int tiles = (N_NODES + 63) / 64;    // 1563 GEMM tiles
    // layer 0: agg -> h1 (free), gemm -> h0
    gather_kernel<<<GB, 256, 0, stream>>>(xb, h1, cnt, bucket);
    gemm_hidden_kernel<<<tiles, 256, 0, stream>>>(h1, xb, h0, Wt0, b0);
    // layer 1: agg -> xb (free), gemm -> h1
    gather_kernel<<<GB, 256, 0, stream>>>(h0, xb, cnt, bucket);
    gemm_hidden_kernel<<<tiles, 256, 0, stream>>>(xb, h0, h1, Wt1, b1);
    // layer 2: agg -> h0 (free), gemm -> out
    gather_kernel<<<GB, 256, 0, stream>>>(h1, h0, cnt, bucket);
    gemm_out_kernel<<<tiles, 256, 0, stream>>>(h0, h1, outp, Wt2, b2);
}